// Round 13
// baseline (1360.926 us; speedup 1.0000x reference)
//
#include <hip/hip_runtime.h>
#include <stdint.h>

#define NLV 8
#define KCB 1024
#define DM  512
#define NTOK (8*4096)
#define BETA 0.00390625f   // 2^-8 bias keeps lo-planes f16-normal; folds into c2'

typedef _Float16 f16;
typedef f16  f16x4 __attribute__((ext_vector_type(4)));
typedef f16  f16x8 __attribute__((ext_vector_type(8)));
typedef float f32x4 __attribute__((ext_vector_type(4)));

typedef __attribute__((address_space(1))) const unsigned int* as1p;
typedef __attribute__((address_space(3))) unsigned int*       as3p;
__device__ __forceinline__ void gll16(const void* g, void* l) {
    __builtin_amdgcn_global_load_lds((as1p)g, (as3p)l, 16, 0, 0);
}

// ---------------- c2' precompute: sum(c^2) + 2*beta*sum(f16(c)) ----------------
__global__ void c2_kernel(const float* __restrict__ cbs, float* __restrict__ c2) {
    int row  = blockIdx.x;
    int lane = threadIdx.x;
    const float4* p4 = (const float4*)(cbs + (size_t)row * DM);
    float4 a = p4[lane];
    float4 b = p4[lane + 64];
    float s = a.x*a.x + a.y*a.y + a.z*a.z + a.w*a.w
            + b.x*b.x + b.y*b.y + b.z*b.z + b.w*b.w;
    float t = (float)(f16)a.x + (float)(f16)a.y + (float)(f16)a.z + (float)(f16)a.w
            + (float)(f16)b.x + (float)(f16)b.y + (float)(f16)b.z + (float)(f16)b.w;
    #pragma unroll
    for (int off = 32; off > 0; off >>= 1) {
        s += __shfl_down(s, off, 64);
        t += __shfl_down(t, off, 64);
    }
    if (lane == 0) c2[row] = s + 2.0f * BETA * t;
}

// ---------------- hi/lo split with bias ----------------
__global__ void split_kernel(const float* __restrict__ src,
                             f16* __restrict__ hi, f16* __restrict__ lo) {
    size_t i = (size_t)blockIdx.x * 256 + threadIdx.x;   // float4 index
    float4 v = ((const float4*)src)[i];
    f16x4 h, l;
    h.x = (f16)v.x; l.x = (f16)((v.x - (float)h.x) + BETA);
    h.y = (f16)v.y; l.y = (f16)((v.y - (float)h.y) + BETA);
    h.z = (f16)v.z; l.z = (f16)((v.z - (float)h.z) + BETA);
    h.w = (f16)v.w; l.w = (f16)((v.w - (float)h.w) + BETA);
    ((f16x4*)hi)[i] = h;
    ((f16x4*)lo)[i] = l;
}

// ---------------- fused all-levels MFMA kernel ----------------
// Round 13: LEVEL FUSION on the verified R7 body. Blocks are token-disjoint
// (block b's residual update touches only its own 128 tokens), so the level
// loop needs NO inter-block sync — the 8 separate dispatches imposed 7
// unnecessary grid-wide barriers (launch overhead + all-block tail sync) and
// 7 cold prologues. Fused: per-block lvl loop; next level's B-staging
// (codebooks, independent of the residual) issues during the current
// epilogue so each level starts hot; A-staging issues after the residual
// writes are drained + __threadfence() (replaces the cross-kernel boundary's
// visibility guarantee; own-CU stores also invalidate local L1 lines).
// Argmin overlay moved to buf1 (frees buf0 for the B prefetch).
// Per-level math is bit-identical to R7 (137.5us/dispatch, VGPR 92,
// 0 conflicts). Geometry: M=128 tok/block (256 blocks = 1/CU), 512 thr =
// 8 waves (2M x 4N), acc[4][4], LDS 2x48KB dbuf, 6 gll/wave staging,
// granule swizzle sg=(lane&3)^((lane>>3)&3), __syncthreads-BEFORE-stage.
#define MBT  128
#define NCH  256
#define KS   32
#define NTHR 512
#define BUFB 49152   // Ahi 8K | Alo 8K | Bh 16K | Bl 16K

__global__ __launch_bounds__(NTHR, 2)
void rvq_fused(const float* __restrict__ xin, float* __restrict__ qout,
               const float* __restrict__ cbs,
               const f16* __restrict__ Bhi, const f16* __restrict__ Blo,
               f16* __restrict__ Ahi, f16* __restrict__ Alo,
               const float* __restrict__ c2g, float* __restrict__ idxout)
{
    __shared__ char smem[2 * BUFB];      // 98304 B -> 1 block/CU
    const int tid  = threadIdx.x;
    const int lane = tid & 63;
    const int w    = tid >> 6;           // 0..7
    const int wn   = w & 3;              // N strip (64 codebooks)
    const int wm   = w >> 2;             // M half (64 tokens)
    const int tx   = lane & 15;
    const int q    = lane >> 4;
    const size_t tok0 = (size_t)blockIdx.x * MBT;

    // ---- staging geometry (identical to R7) ----
    const int rloc = lane >> 2;                      // 0..15
    const int sg   = (lane & 3) ^ ((lane >> 3) & 3);
    const int rsw  = q ^ ((tx >> 1) & 3);            // read-side granule pos

    const f16* pAh = Ahi + (tok0 + w * 16 + rloc) * (size_t)DM + sg * 8;
    const f16* pAl = Alo + (tok0 + w * 16 + rloc) * (size_t)DM + sg * 8;
    const size_t bRow = (size_t)(w * 16 + rloc) * DM + sg * 8;

    // read-side fragment byte offsets
    int aoff[4], boff[4];
    #pragma unroll
    for (int i = 0; i < 4; ++i) aoff[i] = (wm * 64 + i * 16 + tx) * 64 + rsw * 16;
    #pragma unroll
    for (int j = 0; j < 4; ++j) boff[j] = (wn * 64 + j * 16 + tx) * 64 + rsw * 16;

    // overlay on buf1 (last read at gk=63, drained by epilogue's first sync)
    float* redV = (float*)(smem + BUFB);          // [4 wn][128 m]  2 KB
    int*   redI = (int*)(smem + BUFB + 2048);     // 2 KB
    int*   kbst = (int*)(smem + BUFB + 4096);     // 128 ints

    for (int lvl = 0; lvl < NLV; ++lvl) {
        const f16*   Bh_l = Bhi + (size_t)lvl * KCB * DM;
        const f16*   Bl_l = Blo + (size_t)lvl * KCB * DM;
        const float* c2l  = c2g + lvl * KCB;
        const float* cbl  = cbs + (size_t)lvl * KCB * DM;

        auto stageB = [&](char* buf, int gk2, const f16* bh_p, const f16* bl_p) {
            const int ko    = (gk2 & 15) * KS;
            const size_t bo = (size_t)((gk2 >> 4) * NCH) * DM + ko;
            gll16(bh_p + bo + bRow,            buf + 16384 + w * 1024);
            gll16(bh_p + bo + bRow + 128 * DM, buf + 16384 + (w + 8) * 1024);
            gll16(bl_p + bo + bRow,            buf + 32768 + w * 1024);
            gll16(bl_p + bo + bRow + 128 * DM, buf + 32768 + (w + 8) * 1024);
        };
        auto stageA = [&](char* buf, int gk2) {
            const int ko = (gk2 & 15) * KS;
            gll16(pAh + ko, buf + w * 1024);
            gll16(pAl + ko, buf + 8192 + w * 1024);
        };

        if (lvl == 0) {                  // later levels: prefetched in epilogue
            stageB(smem, 0, Bh_l, Bl_l);
            stageA(smem, 0);
        }

        float bestv[16];
        int   besti[16];
        #pragma unroll
        for (int t = 0; t < 16; ++t) { bestv[t] = 3.4e38f; besti[t] = 0; }

        for (int ch = 0; ch < KCB / NCH; ++ch) {
            f32x4 acc[4][4];
            #pragma unroll
            for (int i = 0; i < 4; ++i)
                #pragma unroll
                for (int j = 0; j < 4; ++j) acc[i][j] = (f32x4)0.0f;

            for (int kk = 0; kk < 16; ++kk) {
                const int gk = ch * 16 + kk;             // 0..63
                char* bb = smem + (gk & 1) * BUFB;
                char* bn = smem + ((gk & 1) ^ 1) * BUFB;

                __syncthreads();                         // drains gk-1 prefetch
                                                         // AND all reads of bn
                if (gk + 1 < 64) {
                    stageB(bn, gk + 1, Bh_l, Bl_l);
                    stageA(bn, gk + 1);
                }

                f16x8 ah[4], al[4], bh[4], bl[4];
                #pragma unroll
                for (int i = 0; i < 4; ++i) {
                    ah[i] = *(const f16x8*)(bb + aoff[i]);
                    al[i] = *(const f16x8*)(bb + 8192 + aoff[i]);
                }
                #pragma unroll
                for (int j = 0; j < 4; ++j) {
                    bh[j] = *(const f16x8*)(bb + 16384 + boff[j]);
                    bl[j] = *(const f16x8*)(bb + 32768 + boff[j]);
                }

                __builtin_amdgcn_s_setprio(1);
                #pragma unroll
                for (int j = 0; j < 4; ++j)
                    #pragma unroll
                    for (int i = 0; i < 4; ++i)
                        acc[i][j] = __builtin_amdgcn_mfma_f32_16x16x32_f16(ah[i], bh[j], acc[i][j], 0, 0, 0);
                #pragma unroll
                for (int j = 0; j < 4; ++j)
                    #pragma unroll
                    for (int i = 0; i < 4; ++i)
                        acc[i][j] = __builtin_amdgcn_mfma_f32_16x16x32_f16(ah[i], bl[j], acc[i][j], 0, 0, 0);
                #pragma unroll
                for (int j = 0; j < 4; ++j)
                    #pragma unroll
                    for (int i = 0; i < 4; ++i)
                        acc[i][j] = __builtin_amdgcn_mfma_f32_16x16x32_f16(al[i], bh[j], acc[i][j], 0, 0, 0);
                __builtin_amdgcn_s_setprio(0);
            }

            // chunk argmin (C/D: col=lane&15 -> cb, row=(lane>>4)*4+reg -> token)
            const int cb0 = ch * NCH;
            #pragma unroll
            for (int j = 0; j < 4; ++j) {
                int n = cb0 + wn * 64 + j * 16 + tx;
                float c2v = c2l[n];
                #pragma unroll
                for (int i = 0; i < 4; ++i)
                    #pragma unroll
                    for (int r = 0; r < 4; ++r) {
                        float s = fmaf(-2.f, acc[i][j][r], c2v);
                        int t = i * 4 + r;
                        if (s < bestv[t]) { bestv[t] = s; besti[t] = n; }
                    }
            }
        }

        // cross-lane argmin over tx
        #pragma unroll
        for (int t = 0; t < 16; ++t) {
            float v = bestv[t]; int bi = besti[t];
            #pragma unroll
            for (int off = 1; off < 16; off <<= 1) {
                float ov = __shfl_xor(v, off, 64);
                int   oi = __shfl_xor(bi, off, 64);
                if (ov < v || (ov == v && oi < bi)) { v = ov; bi = oi; }
            }
            bestv[t] = v; besti[t] = bi;
        }

        // ---- epilogue: reduce on buf1 overlay; prefetch next level's B into buf0 ----
        __syncthreads();                 // drains gk=63 reads (buf1 free) + buf0 free
        if (lvl + 1 < NLV)               // B is residual-independent: issue early
            stageB(smem, 0, Bh_l + (size_t)KCB * DM, Bl_l + (size_t)KCB * DM);
        if (tx == 0) {
            #pragma unroll
            for (int i = 0; i < 4; ++i)
                #pragma unroll
                for (int r = 0; r < 4; ++r) {
                    int m = wm * 64 + i * 16 + q * 4 + r;
                    redV[wn * 128 + m] = bestv[i * 4 + r];
                    redI[wn * 128 + m] = besti[i * 4 + r];
                }
        }
        __syncthreads();
        if (tid < MBT) {
            float bv = redV[tid]; int bi = redI[tid];
            #pragma unroll
            for (int ww = 1; ww < 4; ++ww) {
                float v  = redV[ww * 128 + tid];
                int   ii = redI[ww * 128 + tid];
                if (v < bv || (v == bv && ii < bi)) { bv = v; bi = ii; }
            }
            kbst[tid] = bi;
            idxout[(tok0 + tid) * NLV + lvl] = (float)bi;
        }
        __syncthreads();

        // residual update on biased hi/lo planes: r = hi + (lo - beta) - c
        const int is_last = (lvl == NLV - 1);
        #pragma unroll 4
        for (int it = 0; it < 16; ++it) {
            int e  = it * NTHR + tid;          // 128 tok x 64 granules of 8
            int t  = e >> 6, d8 = e & 63;
            size_t go = (tok0 + t) * (size_t)DM + d8 * 8;
            f16x8 h8 = *(const f16x8*)&Ahi[go];
            f16x8 l8 = *(const f16x8*)&Alo[go];
            const float* cp = &cbl[(size_t)kbst[t] * DM + d8 * 8];
            float4 c0 = *(const float4*)cp;
            float4 c1 = *(const float4*)(cp + 4);
            float r[8];
            r[0] = (float)h8[0] + ((float)l8[0] - BETA) - c0.x;
            r[1] = (float)h8[1] + ((float)l8[1] - BETA) - c0.y;
            r[2] = (float)h8[2] + ((float)l8[2] - BETA) - c0.z;
            r[3] = (float)h8[3] + ((float)l8[3] - BETA) - c0.w;
            r[4] = (float)h8[4] + ((float)l8[4] - BETA) - c1.x;
            r[5] = (float)h8[5] + ((float)l8[5] - BETA) - c1.y;
            r[6] = (float)h8[6] + ((float)l8[6] - BETA) - c1.z;
            r[7] = (float)h8[7] + ((float)l8[7] - BETA) - c1.w;
            if (is_last) {
                float4 x0 = *(const float4*)&xin[go];
                float4 x1 = *(const float4*)&xin[go + 4];
                float4 q0 = make_float4(x0.x - r[0], x0.y - r[1], x0.z - r[2], x0.w - r[3]);
                float4 q1 = make_float4(x1.x - r[4], x1.y - r[5], x1.z - r[6], x1.w - r[7]);
                *(float4*)&qout[go]     = q0;
                *(float4*)&qout[go + 4] = q1;
            } else {
                f16x8 h, l;
                #pragma unroll
                for (int k = 0; k < 8; ++k) {
                    h[k] = (f16)r[k];
                    l[k] = (f16)((r[k] - (float)h[k]) + BETA);
                }
                *(f16x8*)&Ahi[go] = h;
                *(f16x8*)&Alo[go] = l;
            }
        }

        if (lvl + 1 < NLV) {
            // make residual stores visible to our own global_load_lds reads
            // (replaces the cross-kernel boundary's guarantee)
            __threadfence();
            __syncthreads();
            stageA(smem, 0);             // fresh A for next level's gk=0
        }
    }
}

// =================== launch ===================
extern "C" void kernel_launch(void* const* d_in, const int* in_sizes, int n_in,
                              void* d_out, int out_size, void* d_ws, size_t ws_size,
                              hipStream_t stream) {
    const float* x   = (const float*)d_in[0];   // [8,4096,512]
    const float* cbs = (const float*)d_in[1];   // [8,1024,512]
    float* qout   = (float*)d_out;                       // [8,4096,512]
    float* idxout = qout + (size_t)NTOK * DM;            // [8,4096,8] as float

    const size_t B_ELE = (size_t)NLV * KCB * DM;   // 4,194,304
    const size_t A_ELE = (size_t)NTOK * DM;        // 16,777,216

    f16* Bhi = (f16*)d_ws;
    f16* Blo = Bhi + B_ELE;
    f16* Ahi = Blo + B_ELE;
    f16* Alo = Ahi + A_ELE;
    float* c2 = (float*)(Alo + A_ELE);

    split_kernel<<<(int)(B_ELE / 4 / 256), 256, 0, stream>>>(cbs, Bhi, Blo);
    split_kernel<<<(int)(A_ELE / 4 / 256), 256, 0, stream>>>(x, Ahi, Alo);
    c2_kernel<<<NLV * KCB, 64, 0, stream>>>(cbs, c2);

    rvq_fused<<<NTOK / MBT, NTHR, 0, stream>>>(x, qout, cbs,
                                               Bhi, Blo, Ahi, Alo, c2, idxout);
}

// Round 14
// 1097.953 us; speedup vs baseline: 1.2395x; 1.2395x over previous
//
#include <hip/hip_runtime.h>
#include <stdint.h>

#define NLV 8
#define KCB 1024
#define DM  512
#define NTOK (8*4096)
#define BETA 0.00390625f   // 2^-8 bias keeps lo-planes f16-normal; folds into c2'

typedef _Float16 f16;
typedef f16  f16x4 __attribute__((ext_vector_type(4)));
typedef f16  f16x8 __attribute__((ext_vector_type(8)));
typedef float f32x4 __attribute__((ext_vector_type(4)));

typedef __attribute__((address_space(1))) const unsigned int* as1p;
typedef __attribute__((address_space(3))) unsigned int*       as3p;
__device__ __forceinline__ void gll16(const void* g, void* l) {
    __builtin_amdgcn_global_load_lds((as1p)g, (as3p)l, 16, 0, 0);
}

// ---------------- c2' precompute: sum(c^2) + 2*beta*sum(f16(c)) ----------------
__global__ void c2_kernel(const float* __restrict__ cbs, float* __restrict__ c2) {
    int row  = blockIdx.x;
    int lane = threadIdx.x;
    const float4* p4 = (const float4*)(cbs + (size_t)row * DM);
    float4 a = p4[lane];
    float4 b = p4[lane + 64];
    float s = a.x*a.x + a.y*a.y + a.z*a.z + a.w*a.w
            + b.x*b.x + b.y*b.y + b.z*b.z + b.w*b.w;
    float t = (float)(f16)a.x + (float)(f16)a.y + (float)(f16)a.z + (float)(f16)a.w
            + (float)(f16)b.x + (float)(f16)b.y + (float)(f16)b.z + (float)(f16)b.w;
    #pragma unroll
    for (int off = 32; off > 0; off >>= 1) {
        s += __shfl_down(s, off, 64);
        t += __shfl_down(t, off, 64);
    }
    if (lane == 0) c2[row] = s + 2.0f * BETA * t;
}

// ---------------- hi/lo split with bias ----------------
__global__ void split_kernel(const float* __restrict__ src,
                             f16* __restrict__ hi, f16* __restrict__ lo) {
    size_t i = (size_t)blockIdx.x * 256 + threadIdx.x;   // float4 index
    float4 v = ((const float4*)src)[i];
    f16x4 h, l;
    h.x = (f16)v.x; l.x = (f16)((v.x - (float)h.x) + BETA);
    h.y = (f16)v.y; l.y = (f16)((v.y - (float)h.y) + BETA);
    h.z = (f16)v.z; l.z = (f16)((v.z - (float)h.z) + BETA);
    h.w = (f16)v.w; l.w = (f16)((v.w - (float)h.w) + BETA);
    ((f16x4*)hi)[i] = h;
    ((f16x4*)lo)[i] = l;
}

// ---------------- main MFMA level kernel ----------------
// FINAL (R14) = R7/R12 restored verbatim — the session's verified best:
// 1128 us total, 137.5 us/dispatch, VGPR 92, 0 bank conflicts, no spill.
// Session ledger (falsified axes for this structure): barrier schedule
// (R2/R9), occupancy 8<->16 waves/CU (R5/R6), staged volume (R7, -4% = the
// one real win), register operand prefetch (R8), phase-split+counted vmcnt
// (R9, -15%), 32x32 MFMA shape (R11, swizzle-broken), level fusion (R13,
// -19%: per-level cost rose 137.5->163 us; the 8-dispatch version gets free
// cross-level pipelining from the command processor). The kstep period
// (~5150 cyc) is the serial pipe sum — the documented m97-structure plateau
// (~36% dense MFMA peak); the known escape (8-phase 256^2 co-designed
// template) does not fit this problem's LDS budget (hi/lo split doubles
// tile bytes -> 256KB > 160KB).
// Geometry: M=128 tok/block (256 blocks = 1/CU), 512 thr = 8 waves (2M x
// 4N), each wave 64 tok x 64 cb (acc[4][4]). LDS 2x48KB dbuf. Staging 6
// gll/wave (Ahi,Alo chunk w; Bh chunks w,w+8; Bl chunks w,w+8), granule
// swizzle sg=(lane&3)^((lane>>3)&3), 0 conflicts. Race-free sync:
// __syncthreads BEFORE stage (no wave writes a buffer until all waves'
// reads of it completed — forced by MFMA consumption before barrier).
#define MBT  128
#define NCH  256
#define KS   32
#define NTHR 512
#define BUFB 49152   // Ahi 8K | Alo 8K | Bh 16K | Bl 16K

__global__ __launch_bounds__(NTHR, 2)
void rvq_mfma(const float* __restrict__ xin, float* __restrict__ qout,
              const float* __restrict__ cbs,
              const f16* __restrict__ Bhi, const f16* __restrict__ Blo,
              f16* __restrict__ Ahi, f16* __restrict__ Alo,
              const float* __restrict__ c2g, float* __restrict__ idxout,
              int lvl, int is_last)
{
    __shared__ char smem[2 * BUFB];      // 98304 B -> 1 block/CU
    const int tid  = threadIdx.x;
    const int lane = tid & 63;
    const int w    = tid >> 6;           // 0..7
    const int wn   = w & 3;              // N strip (64 codebooks)
    const int wm   = w >> 2;             // M half (64 tokens)
    const int tx   = lane & 15;
    const int q    = lane >> 4;
    const size_t tok0 = (size_t)blockIdx.x * MBT;

    const f16*   Bh_l = Bhi + (size_t)lvl * KCB * DM;
    const f16*   Bl_l = Blo + (size_t)lvl * KCB * DM;
    const float* c2l  = c2g + lvl * KCB;
    const float* cbl  = cbs + (size_t)lvl * KCB * DM;

    // ---- staging (6 gll per wave, 48 x 1KB chunks per buffer) ----
    // chunk = 16 rows x 64 B (one kstep K-slice). lane l covers row l>>2,
    // granule-pos l&3; fetched data-granule sg = (l&3)^((l>>3)&3)
    // (chunk bases are multiples of 16 rows so only l contributes).
    const int rloc = lane >> 2;                      // 0..15
    const int sg   = (lane & 3) ^ ((lane >> 3) & 3);
    const int rsw  = q ^ ((tx >> 1) & 3);            // read-side granule pos

    // per-thread base pointers (hoist 64-bit math out of the loop)
    const f16* pAh = Ahi + (tok0 + w * 16 + rloc) * (size_t)DM + sg * 8;
    const f16* pAl = Alo + (tok0 + w * 16 + rloc) * (size_t)DM + sg * 8;
    const size_t bRow = (size_t)(w * 16 + rloc) * DM + sg * 8;

    auto stage = [&](char* buf, int gk2) {
        const int ko    = (gk2 & 15) * KS;                       // scalar
        const size_t bo = (size_t)((gk2 >> 4) * NCH) * DM + ko;  // scalar
        gll16(pAh + ko, buf + w * 1024);
        gll16(pAl + ko, buf + 8192 + w * 1024);
        gll16(Bh_l + bo + bRow,            buf + 16384 + w * 1024);
        gll16(Bh_l + bo + bRow + 128 * DM, buf + 16384 + (w + 8) * 1024);
        gll16(Bl_l + bo + bRow,            buf + 32768 + w * 1024);
        gll16(Bl_l + bo + bRow + 128 * DM, buf + 32768 + (w + 8) * 1024);
    };

    // ---- read-side fragment byte offsets ----
    int aoff[4], boff[4];
    #pragma unroll
    for (int i = 0; i < 4; ++i) aoff[i] = (wm * 64 + i * 16 + tx) * 64 + rsw * 16;
    #pragma unroll
    for (int j = 0; j < 4; ++j) boff[j] = (wn * 64 + j * 16 + tx) * 64 + rsw * 16;

    float bestv[16];
    int   besti[16];
    #pragma unroll
    for (int t = 0; t < 16; ++t) { bestv[t] = 3.4e38f; besti[t] = 0; }

    stage(smem, 0);   // prologue: buf0 for gk=0 (drained by first syncthreads)

    for (int ch = 0; ch < KCB / NCH; ++ch) {
        f32x4 acc[4][4];
        #pragma unroll
        for (int i = 0; i < 4; ++i)
            #pragma unroll
            for (int j = 0; j < 4; ++j) acc[i][j] = (f32x4)0.0f;

        for (int kk = 0; kk < 16; ++kk) {
            const int gk = ch * 16 + kk;             // 0..63
            char* bb = smem + (gk & 1) * BUFB;
            char* bn = smem + ((gk & 1) ^ 1) * BUFB;

            __syncthreads();                         // drains gk-1 prefetch AND
                                                     // all waves' reads of bn
            if (gk + 1 < 64)
                stage(bn, gk + 1);                   // 6 loads (k+1)

            f16x8 ah[4], al[4], bh[4], bl[4];
            #pragma unroll
            for (int i = 0; i < 4; ++i) {
                ah[i] = *(const f16x8*)(bb + aoff[i]);
                al[i] = *(const f16x8*)(bb + 8192 + aoff[i]);
            }
            #pragma unroll
            for (int j = 0; j < 4; ++j) {
                bh[j] = *(const f16x8*)(bb + 16384 + boff[j]);
                bl[j] = *(const f16x8*)(bb + 32768 + boff[j]);
            }

            __builtin_amdgcn_s_setprio(1);
            #pragma unroll
            for (int j = 0; j < 4; ++j)
                #pragma unroll
                for (int i = 0; i < 4; ++i)
                    acc[i][j] = __builtin_amdgcn_mfma_f32_16x16x32_f16(ah[i], bh[j], acc[i][j], 0, 0, 0);
            #pragma unroll
            for (int j = 0; j < 4; ++j)
                #pragma unroll
                for (int i = 0; i < 4; ++i)
                    acc[i][j] = __builtin_amdgcn_mfma_f32_16x16x32_f16(ah[i], bl[j], acc[i][j], 0, 0, 0);
            #pragma unroll
            for (int j = 0; j < 4; ++j)
                #pragma unroll
                for (int i = 0; i < 4; ++i)
                    acc[i][j] = __builtin_amdgcn_mfma_f32_16x16x32_f16(al[i], bh[j], acc[i][j], 0, 0, 0);
            __builtin_amdgcn_s_setprio(0);
        }

        // chunk argmin epilogue (C/D: col=lane&15 -> cb, row=(lane>>4)*4+reg -> token)
        const int cb0 = ch * NCH;
        #pragma unroll
        for (int j = 0; j < 4; ++j) {
            int n = cb0 + wn * 64 + j * 16 + tx;
            float c2v = c2l[n];
            #pragma unroll
            for (int i = 0; i < 4; ++i)
                #pragma unroll
                for (int r = 0; r < 4; ++r) {
                    float s = fmaf(-2.f, acc[i][j][r], c2v);
                    int t = i * 4 + r;
                    if (s < bestv[t]) { bestv[t] = s; besti[t] = n; }
                }
        }
    }

    // cross-lane argmin over tx (16 lanes; same q -> same token rows)
    #pragma unroll
    for (int t = 0; t < 16; ++t) {
        float v = bestv[t]; int bi = besti[t];
        #pragma unroll
        for (int off = 1; off < 16; off <<= 1) {
            float ov = __shfl_xor(v, off, 64);
            int   oi = __shfl_xor(bi, off, 64);
            if (ov < v || (ov == v && oi < bi)) { v = ov; bi = oi; }
        }
        bestv[t] = v; besti[t] = bi;
    }

    // cross-wave reduce over the 4 wn strips; overlay on buf0 (reads retired,
    // __syncthreads drains all outstanding ops first).
    float* redV = (float*)smem;            // [4 wn][128 m]  2 KB
    int*   redI = (int*)(smem + 2048);     // 2 KB
    int*   kbst = (int*)(smem + 4096);     // 128 ints
    __syncthreads();
    if (tx == 0) {
        #pragma unroll
        for (int i = 0; i < 4; ++i)
            #pragma unroll
            for (int r = 0; r < 4; ++r) {
                int m = wm * 64 + i * 16 + q * 4 + r;
                redV[wn * 128 + m] = bestv[i * 4 + r];
                redI[wn * 128 + m] = besti[i * 4 + r];
            }
    }
    __syncthreads();
    if (tid < MBT) {
        float bv = redV[tid]; int bi = redI[tid];
        #pragma unroll
        for (int ww = 1; ww < 4; ++ww) {
            float v  = redV[ww * 128 + tid];
            int   ii = redI[ww * 128 + tid];
            if (v < bv || (v == bv && ii < bi)) { bv = v; bi = ii; }
        }
        kbst[tid] = bi;
        idxout[(tok0 + tid) * NLV + lvl] = (float)bi;
    }
    __syncthreads();

    // residual update on biased hi/lo planes: r = hi + (lo - beta) - c
    #pragma unroll 4
    for (int it = 0; it < 16; ++it) {
        int e  = it * NTHR + tid;          // 128 tok x 64 granules of 8
        int t  = e >> 6, d8 = e & 63;
        size_t go = (tok0 + t) * (size_t)DM + d8 * 8;
        f16x8 h8 = *(const f16x8*)&Ahi[go];
        f16x8 l8 = *(const f16x8*)&Alo[go];
        const float* cp = &cbl[(size_t)kbst[t] * DM + d8 * 8];
        float4 c0 = *(const float4*)cp;
        float4 c1 = *(const float4*)(cp + 4);
        float r[8];
        r[0] = (float)h8[0] + ((float)l8[0] - BETA) - c0.x;
        r[1] = (float)h8[1] + ((float)l8[1] - BETA) - c0.y;
        r[2] = (float)h8[2] + ((float)l8[2] - BETA) - c0.z;
        r[3] = (float)h8[3] + ((float)l8[3] - BETA) - c0.w;
        r[4] = (float)h8[4] + ((float)l8[4] - BETA) - c1.x;
        r[5] = (float)h8[5] + ((float)l8[5] - BETA) - c1.y;
        r[6] = (float)h8[6] + ((float)l8[6] - BETA) - c1.z;
        r[7] = (float)h8[7] + ((float)l8[7] - BETA) - c1.w;
        if (is_last) {
            float4 x0 = *(const float4*)&xin[go];
            float4 x1 = *(const float4*)&xin[go + 4];
            float4 q0 = make_float4(x0.x - r[0], x0.y - r[1], x0.z - r[2], x0.w - r[3]);
            float4 q1 = make_float4(x1.x - r[4], x1.y - r[5], x1.z - r[6], x1.w - r[7]);
            *(float4*)&qout[go]     = q0;
            *(float4*)&qout[go + 4] = q1;
        } else {
            f16x8 h, l;
            #pragma unroll
            for (int k = 0; k < 8; ++k) {
                h[k] = (f16)r[k];
                l[k] = (f16)((r[k] - (float)h[k]) + BETA);
            }
            *(f16x8*)&Ahi[go] = h;
            *(f16x8*)&Alo[go] = l;
        }
    }
}

// =================== launch ===================
extern "C" void kernel_launch(void* const* d_in, const int* in_sizes, int n_in,
                              void* d_out, int out_size, void* d_ws, size_t ws_size,
                              hipStream_t stream) {
    const float* x   = (const float*)d_in[0];   // [8,4096,512]
    const float* cbs = (const float*)d_in[1];   // [8,1024,512]
    float* qout   = (float*)d_out;                       // [8,4096,512]
    float* idxout = qout + (size_t)NTOK * DM;            // [8,4096,8] as float

    const size_t B_ELE = (size_t)NLV * KCB * DM;   // 4,194,304
    const size_t A_ELE = (size_t)NTOK * DM;        // 16,777,216

    f16* Bhi = (f16*)d_ws;
    f16* Blo = Bhi + B_ELE;
    f16* Ahi = Blo + B_ELE;
    f16* Alo = Ahi + A_ELE;
    float* c2 = (float*)(Alo + A_ELE);

    split_kernel<<<(int)(B_ELE / 4 / 256), 256, 0, stream>>>(cbs, Bhi, Blo);
    split_kernel<<<(int)(A_ELE / 4 / 256), 256, 0, stream>>>(x, Ahi, Alo);
    c2_kernel<<<NLV * KCB, 64, 0, stream>>>(cbs, c2);

    const int nblocks = NTOK / MBT;  // 256 -> 1 block/CU
    for (int l = 0; l < NLV; ++l) {
        rvq_mfma<<<nblocks, NTHR, 0, stream>>>(x, qout, cbs,
                                               Bhi, Blo, Ahi, Alo, c2, idxout,
                                               l, (l == NLV - 1) ? 1 : 0);
    }
}